// Round 1
// baseline (971.027 us; speedup 1.0000x reference)
//
#include <hip/hip_runtime.h>
#include <hip/hip_bf16.h>
#include <cstdint>
#include <cstddef>

// GPTQ int4 linear: out[T,N] = x[T,K] @ dequant(qweight,qzeros,scales)
// T=8192, K=4096, N=11008, GROUP=128, 4-bit nibbles.
// Strategy: x->bf16, dequant->W^T[N,K] bf16, then bf16 MFMA GEMM (m97-class
// 128x128 tile, BK=64, global_load_lds width 16, XOR-swizzled LDS).

#define K_DIM 4096
#define N_DIM 11008
#define GROUP_SZ 128

typedef __bf16 bf16x8_t __attribute__((ext_vector_type(8)));
typedef float f32x4_t __attribute__((ext_vector_type(4)));

__device__ __forceinline__ void async_copy16(const void* g, void* l) {
    __builtin_amdgcn_global_load_lds((const __attribute__((address_space(1))) void*)g,
                                     (__attribute__((address_space(3))) void*)l,
                                     16, 0, 0);
}

// ---------------- x fp32 -> bf16 (vectorized) ----------------
__global__ __launch_bounds__(256) void convert_x_kernel(const float* __restrict__ x,
                                                        __bf16* __restrict__ xb,
                                                        long total) {
    long i = ((long)blockIdx.x * 256 + threadIdx.x) * 8;
    if (i >= total) return;
    const float4* p = (const float4*)(x + i);
    float4 u = p[0], v = p[1];
    bf16x8_t o;
    o[0] = (__bf16)u.x; o[1] = (__bf16)u.y; o[2] = (__bf16)u.z; o[3] = (__bf16)u.w;
    o[4] = (__bf16)v.x; o[5] = (__bf16)v.y; o[6] = (__bf16)v.z; o[7] = (__bf16)v.w;
    *(bf16x8_t*)(xb + i) = o;
}

// ---------------- GPTQ dequant -> W^T [N][K] bf16 ----------------
// Tile: 128 n x 128 k per block (one k-tile == one GROUP exactly).
// Reads qweight coalesced along N, transposes through LDS, writes W^T rows
// (256B contiguous per n) coalesced along K.
__global__ __launch_bounds__(256) void dequant_kernel(const int* __restrict__ qw,
                                                      const int* __restrict__ qz,
                                                      const float* __restrict__ sc,
                                                      __bf16* __restrict__ Wt) {
    __shared__ __align__(16) __bf16 sT[128 * 136];  // [n][k] pad +8 bf16
    __shared__ float sS[128];
    __shared__ float sB[128];
    const int n0 = blockIdx.x * 128;
    const int g  = blockIdx.y;          // group index == k-tile index (k0 = g*128)
    const int t  = threadIdx.x;

    if (t < 128) {
        int n = n0 + t;
        float s = sc[(size_t)g * N_DIM + n];
        int z = (qz[(size_t)g * (N_DIM / 8) + (n >> 3)] >> ((n & 7) * 4)) & 15;
        sS[t] = s;
        sB[t] = -(float)(z + 1) * s;     // GPTQ +1 zero offset
    }
    __syncthreads();

    // 16 qweight rows (kp = g*16..+15) x 128 cols; 8 int32 per thread.
#pragma unroll
    for (int it = 0; it < 8; ++it) {
        int wi  = it * 256 + t;
        int row = wi >> 7;               // 0..15 (kp sub-row)
        int col = wi & 127;              // n sub-col
        int q = qw[(size_t)(g * 16 + row) * N_DIM + n0 + col];
        float s = sS[col], b = sB[col];
        bf16x8_t v;
#pragma unroll
        for (int j = 0; j < 8; ++j) {
            float w = (float)((q >> (4 * j)) & 15);
            v[j] = (__bf16)fmaf(w, s, b);
        }
        *(bf16x8_t*)(&sT[col * 136 + row * 8]) = v;
    }
    __syncthreads();

    // Write out: thread t -> n_loc = t&127, half = t>>7 ; 128B per thread.
    int n_loc = t & 127, half = t >> 7;
    const __bf16* src = &sT[n_loc * 136 + half * 64];
    __bf16* dst = Wt + (size_t)(n0 + n_loc) * K_DIM + g * GROUP_SZ + half * 64;
#pragma unroll
    for (int i = 0; i < 8; ++i)
        *(bf16x8_t*)(dst + i * 8) = *(const bf16x8_t*)(src + i * 8);
}

// ---------------- bf16 MFMA GEMM: C[T,N] = A[T,K] * Bt[N,K]^T ----------------
// 128x128 tile, BK=64, 4 waves (2x2 of 64x64), 16x16x32 MFMA, swizzled LDS.
__global__ __launch_bounds__(256, 3) void gemm_kernel(const __bf16* __restrict__ A,
                                                      const __bf16* __restrict__ Bt,
                                                      float* __restrict__ C,
                                                      int mtiles) {
    __shared__ __align__(16) __bf16 sA[128 * 64];
    __shared__ __align__(16) __bf16 sB[128 * 64];
    const int tid = threadIdx.x;

    // XCD-aware swizzle (bijective only when nwg % 8 == 0)
    int nwg = gridDim.x;
    int bid = blockIdx.x;
    int swz = (nwg & 7) ? bid : ((bid & 7) * (nwg >> 3) + (bid >> 3));
    int mt = swz % mtiles;
    int nt = swz / mtiles;
    const int row0 = mt * 128;
    const int col0 = nt * 128;

    const char* aPanel = (const char*)(A + (size_t)row0 * K_DIM);
    const char* bPanel = (const char*)(Bt + (size_t)col0 * K_DIM);

    // staging offsets: pass p covers flat-16B index f = p*256+tid
    // LDS dest is linear (f*16); global source gets the inverse XOR swizzle.
    int sOff[4], dOff[4];
#pragma unroll
    for (int p = 0; p < 4; ++p) {
        int f = p * 256 + tid;
        int r = f >> 3, c = f & 7;
        sOff[p] = r * (K_DIM * 2) + ((c * 16) ^ ((r & 7) << 4));
        dOff[p] = f * 16;
    }

    const int lane = tid & 63;
    const int w = tid >> 6;
    const int wm = (w >> 1) * 64, wn = (w & 1) * 64;
    const int lr = lane & 15, lq = lane >> 4;
    const int xm = (lr & 7) << 4;             // XOR mask for swizzled ds_read
    const int kp0 = (lq * 16) ^ xm;           // kk=0 fragment byte offset
    const int kp1 = (64 + lq * 16) ^ xm;      // kk=1
    int aRow[4], bRow[4];
#pragma unroll
    for (int i = 0; i < 4; ++i) {
        aRow[i] = (wm + i * 16 + lr) * 128;   // row stride 64*2 = 128B
        bRow[i] = (wn + i * 16 + lr) * 128;
    }

    f32x4_t acc[4][4];
#pragma unroll
    for (int i = 0; i < 4; ++i)
#pragma unroll
        for (int j = 0; j < 4; ++j)
            acc[i][j] = (f32x4_t){0.f, 0.f, 0.f, 0.f};

    const char* sAc = (const char*)sA;
    const char* sBc = (const char*)sB;

    for (int kt = 0; kt < K_DIM / 64; ++kt) {
        const char* aSrc = aPanel + kt * 128;
        const char* bSrc = bPanel + kt * 128;
#pragma unroll
        for (int p = 0; p < 4; ++p)
            async_copy16(aSrc + sOff[p], (char*)sA + dOff[p]);
#pragma unroll
        for (int p = 0; p < 4; ++p)
            async_copy16(bSrc + sOff[p], (char*)sB + dOff[p]);
        __syncthreads();   // drains vmcnt (global_load_lds) + barrier

        bf16x8_t av[4], bv[4];
        // kk = 0
#pragma unroll
        for (int i = 0; i < 4; ++i) av[i] = *(const bf16x8_t*)(sAc + aRow[i] + kp0);
#pragma unroll
        for (int i = 0; i < 4; ++i) bv[i] = *(const bf16x8_t*)(sBc + bRow[i] + kp0);
#pragma unroll
        for (int i = 0; i < 4; ++i)
#pragma unroll
            for (int j = 0; j < 4; ++j)
                acc[i][j] = __builtin_amdgcn_mfma_f32_16x16x32_bf16(av[i], bv[j], acc[i][j], 0, 0, 0);
        // kk = 1
#pragma unroll
        for (int i = 0; i < 4; ++i) av[i] = *(const bf16x8_t*)(sAc + aRow[i] + kp1);
#pragma unroll
        for (int i = 0; i < 4; ++i) bv[i] = *(const bf16x8_t*)(sBc + bRow[i] + kp1);
#pragma unroll
        for (int i = 0; i < 4; ++i)
#pragma unroll
            for (int j = 0; j < 4; ++j)
                acc[i][j] = __builtin_amdgcn_mfma_f32_16x16x32_bf16(av[i], bv[j], acc[i][j], 0, 0, 0);
        __syncthreads();   // protect LDS before next stage overwrites
    }

    // Epilogue: C/D layout col=lane&15, row=(lane>>4)*4+reg
#pragma unroll
    for (int i = 0; i < 4; ++i) {
        int rbase = row0 + wm + i * 16 + lq * 4;
#pragma unroll
        for (int j = 0; j < 4; ++j) {
            int cidx = col0 + wn + j * 16 + lr;
#pragma unroll
            for (int rg = 0; rg < 4; ++rg)
                C[(size_t)(rbase + rg) * N_DIM + cidx] = acc[i][j][rg];
        }
    }
}

// ---------------- fallback (ws too small): fused fp32 path ----------------
__global__ __launch_bounds__(256) void fallback_kernel(const float* __restrict__ x,
                                                       const int* __restrict__ qw,
                                                       const int* __restrict__ qz,
                                                       const float* __restrict__ sc,
                                                       float* __restrict__ out) {
    __shared__ float xrow[K_DIM];
    const int t = blockIdx.y;
    const int n = blockIdx.x * 256 + threadIdx.x;
    for (int i = threadIdx.x; i < K_DIM; i += 256)
        xrow[i] = x[(size_t)t * K_DIM + i];
    __syncthreads();
    if (n >= N_DIM) return;
    float acc = 0.f;
    for (int g = 0; g < K_DIM / GROUP_SZ; ++g) {
        float s = sc[(size_t)g * N_DIM + n];
        int z = (qz[(size_t)g * (N_DIM / 8) + (n >> 3)] >> ((n & 7) * 4)) & 15;
        float b = -(float)(z + 1) * s;
        for (int kp = g * 16; kp < g * 16 + 16; ++kp) {
            int q = qw[(size_t)kp * N_DIM + n];
#pragma unroll
            for (int j = 0; j < 8; ++j) {
                float w = (float)((q >> (4 * j)) & 15);
                acc = fmaf(xrow[kp * 8 + j], fmaf(w, s, b), acc);
            }
        }
    }
    out[(size_t)t * N_DIM + n] = acc;
}

extern "C" void kernel_launch(void* const* d_in, const int* in_sizes, int n_in,
                              void* d_out, int out_size, void* d_ws, size_t ws_size,
                              hipStream_t stream) {
    const float* x  = (const float*)d_in[0];
    const int*   qw = (const int*)d_in[1];
    const int*   qz = (const int*)d_in[2];
    const float* sc = (const float*)d_in[3];
    float* out = (float*)d_out;

    const long T = (long)in_sizes[0] / K_DIM;   // 8192
    const size_t xb_bytes = (size_t)T * K_DIM * sizeof(__bf16);
    const size_t wt_bytes = (size_t)N_DIM * K_DIM * sizeof(__bf16);

    if (ws_size >= xb_bytes + wt_bytes) {
        __bf16* xb = (__bf16*)d_ws;
        __bf16* Wt = (__bf16*)((char*)d_ws + xb_bytes);
        long total = T * K_DIM;
        long nthr = total / 8;
        convert_x_kernel<<<dim3((unsigned)((nthr + 255) / 256)), dim3(256), 0, stream>>>(x, xb, total);
        dequant_kernel<<<dim3(N_DIM / 128, K_DIM / GROUP_SZ), dim3(256), 0, stream>>>(qw, qz, sc, Wt);
        int mtiles = (int)(T / 128);
        gemm_kernel<<<dim3((unsigned)(mtiles * (N_DIM / 128))), dim3(256), 0, stream>>>(xb, Wt, out, mtiles);
    } else {
        fallback_kernel<<<dim3(N_DIM / 256 + 1, (unsigned)T), dim3(256), 0, stream>>>(x, qw, qz, sc, out);
    }
}

// Round 2
// 808.009 us; speedup vs baseline: 1.2018x; 1.2018x over previous
//
#include <hip/hip_runtime.h>
#include <hip/hip_bf16.h>
#include <cstdint>
#include <cstddef>

// GPTQ int4 linear: out[T,N] = x[T,K] @ dequant(qweight,qzeros,scales)
// T=8192, K=4096, N=11008, GROUP=128.
// Pipeline: x->bf16, dequant->W^T[N,K] bf16, then 256x256-tile 8-wave MFMA GEMM
// with 4-phase/K-tile counted-vmcnt schedule (T2 swizzle + T3/T4 + T5 + banded T1).

#define K_DIM 4096
#define N_DIM 11008
#define GROUP_SZ 128
#define KB (K_DIM * 2)        // bytes per row of a K-major bf16 panel
#define NTILES_K (K_DIM / 64) // 64 K-tiles of BK=64

typedef __bf16 bf16x8_t __attribute__((ext_vector_type(8)));
typedef float f32x4_t __attribute__((ext_vector_type(4)));

__device__ __forceinline__ void async_copy16(const void* g, void* l) {
    __builtin_amdgcn_global_load_lds((const __attribute__((address_space(1))) void*)g,
                                     (__attribute__((address_space(3))) void*)l,
                                     16, 0, 0);
}

// ---------------- x fp32 -> bf16 (vectorized) ----------------
__global__ __launch_bounds__(256) void convert_x_kernel(const float* __restrict__ x,
                                                        __bf16* __restrict__ xb,
                                                        long total) {
    long i = ((long)blockIdx.x * 256 + threadIdx.x) * 8;
    if (i >= total) return;
    const float4* p = (const float4*)(x + i);
    float4 u = p[0], v = p[1];
    bf16x8_t o;
    o[0] = (__bf16)u.x; o[1] = (__bf16)u.y; o[2] = (__bf16)u.z; o[3] = (__bf16)u.w;
    o[4] = (__bf16)v.x; o[5] = (__bf16)v.y; o[6] = (__bf16)v.z; o[7] = (__bf16)v.w;
    *(bf16x8_t*)(xb + i) = o;
}

// ---------------- GPTQ dequant -> W^T [N][K] bf16 ----------------
__global__ __launch_bounds__(256) void dequant_kernel(const int* __restrict__ qw,
                                                      const int* __restrict__ qz,
                                                      const float* __restrict__ sc,
                                                      __bf16* __restrict__ Wt) {
    __shared__ __align__(16) __bf16 dqT[128 * 136];  // [n][k] pad +8 bf16
    __shared__ float dqS[128];
    __shared__ float dqB[128];
    const int n0 = blockIdx.x * 128;
    const int g  = blockIdx.y;          // group index == k-tile (k0 = g*128)
    const int t  = threadIdx.x;

    if (t < 128) {
        int n = n0 + t;
        float s = sc[(size_t)g * N_DIM + n];
        int z = (qz[(size_t)g * (N_DIM / 8) + (n >> 3)] >> ((n & 7) * 4)) & 15;
        dqS[t] = s;
        dqB[t] = -(float)(z + 1) * s;     // GPTQ +1 zero offset
    }
    __syncthreads();

#pragma unroll
    for (int it = 0; it < 8; ++it) {
        int wi  = it * 256 + t;
        int row = wi >> 7;               // 0..15 (kp sub-row)
        int col = wi & 127;              // n sub-col
        int q = qw[(size_t)(g * 16 + row) * N_DIM + n0 + col];
        float s = dqS[col], b = dqB[col];
        bf16x8_t v;
#pragma unroll
        for (int j = 0; j < 8; ++j) {
            float w = (float)((q >> (4 * j)) & 15);
            v[j] = (__bf16)fmaf(w, s, b);
        }
        *(bf16x8_t*)(&dqT[col * 136 + row * 8]) = v;
    }
    __syncthreads();

    int n_loc = t & 127, half = t >> 7;
    const __bf16* src = &dqT[n_loc * 136 + half * 64];
    __bf16* dst = Wt + (size_t)(n0 + n_loc) * K_DIM + g * GROUP_SZ + half * 64;
#pragma unroll
    for (int i = 0; i < 8; ++i)
        *(bf16x8_t*)(dst + i * 8) = *(const bf16x8_t*)(src + i * 8);
}

// ---------------- 256x256 8-wave 4-phase MFMA GEMM ----------------
// C[T,N] = A[T,K] * Bt[N,K]^T.  8 waves as 2(M) x 4(N); wave tile 128x64.
// Per K-tile: 4 phases, each {ds_read quad frags | stage 1 quadrant half-tile |
// counted vmcnt | barrier | setprio+16 MFMA | barrier}.
// Staging order per tile t (into buf t^1): AQ0(t+1),BQ0(t+1),BQ1(t+1),AQ1(t+1).
// Ledger (per-thread, 2 loads/phase): vmcnt(4) at ph0 guards BQ1(t) for ph1
// reads; vmcnt(4) at ph1 guards AQ1(t) for ph2; none at ph2; vmcnt(4) at ph3
// guards AQ0/BQ0(t+1) for next tile's ph0. Never drains to 0.
__global__ __launch_bounds__(512, 2) void gemm256_kernel(const __bf16* __restrict__ A,
                                                         const __bf16* __restrict__ Bt,
                                                         float* __restrict__ C,
                                                         int mtiles, int ntiles) {
    __shared__ __align__(16) char ldsA[2][256 * 128];   // 64 KB
    __shared__ __align__(16) char ldsB[2][256 * 128];   // 64 KB
    const int tid = threadIdx.x;

    // T1: XCD chunking (bijective: grid % 8 == 0 here) + band supertiling for L3.
    const int nwg = gridDim.x;
    const int bid = blockIdx.x;
    int vid = (nwg & 7) ? bid : ((bid & 7) * (nwg >> 3) + (bid >> 3));
    int mt, nt;
    if ((mtiles & 15) == 0) {
        const int bandsz = 16 * ntiles;
        const int band = vid / bandsz, rem = vid % bandsz;
        nt = rem >> 4;
        mt = (band << 4) + (rem & 15);
    } else {
        mt = vid % mtiles;
        nt = vid / mtiles;
    }

    const char* aPanel = (const char*)A + (size_t)mt * 256 * KB;
    const char* bPanel = (const char*)Bt + (size_t)nt * 256 * KB;

    // Staging offsets. Quadrant row maps (preserve row&7 == r&7 so the XOR
    // swizzle mask matches the reader's (row&7)<<4):
    //   A-Q0: r + (r&64)   -> rows {0-63,128-191};  A-Q1 = +64
    //   B-Q0: r + (r&~31)  -> rows {0-31,64-95,128-159,192-223}; B-Q1 = +32
    // LDS dest is LINEAR in lane order (global_load_lds constraint); the
    // inverse XOR swizzle is applied to the GLOBAL source (rule: both-sides).
    int srcA[2], srcB[2], dstA[2], dstB[2];
#pragma unroll
    for (int q = 0; q < 2; ++q) {
        const int f = q * 512 + tid;
        const int r = f >> 3, c = f & 7;
        const int swz = (c * 16) ^ ((r & 7) << 4);
        const int Ra = r + (r & 64);
        const int Rb = r + (r & ~31);
        srcA[q] = Ra * KB + swz;  dstA[q] = Ra * 128 + c * 16;
        srcB[q] = Rb * KB + swz;  dstB[q] = Rb * 128 + c * 16;
    }

    const int lane = tid & 63;
    const int wid = tid >> 6;
    const int wm = wid >> 2, wn = wid & 3;        // 2 x 4 waves
    const int lr = lane & 15, lq = lane >> 4;
    const int kOff0 = (lq * 16) ^ ((lr & 7) << 4);
    const int kOff1 = (64 + lq * 16) ^ ((lr & 7) << 4);
    const int aRowBase = wm * 128 + lr;           // + mq*64 + i*16
    const int bRowBase = wn * 64 + lr;            // + n*16

    bf16x8_t aF[4][2], bF[4][2];
    f32x4_t acc[8][4];
#pragma unroll
    for (int m = 0; m < 8; ++m)
#pragma unroll
        for (int n = 0; n < 4; ++n)
            acc[m][n] = (f32x4_t){0.f, 0.f, 0.f, 0.f};

#define GL_A(KT, BUFS, ROFF) do {                                                          \
    async_copy16(aPanel + (size_t)(KT) * 128 + (ROFF) * KB + srcA[0],                      \
                 &ldsA[BUFS][(ROFF) * 128] + dstA[0]);                                     \
    async_copy16(aPanel + (size_t)(KT) * 128 + (ROFF) * KB + srcA[1],                      \
                 &ldsA[BUFS][(ROFF) * 128] + dstA[1]);                                     \
} while (0)
#define GL_B(KT, BUFS, ROFF) do {                                                          \
    async_copy16(bPanel + (size_t)(KT) * 128 + (ROFF) * KB + srcB[0],                      \
                 &ldsB[BUFS][(ROFF) * 128] + dstB[0]);                                     \
    async_copy16(bPanel + (size_t)(KT) * 128 + (ROFF) * KB + srcB[1],                      \
                 &ldsB[BUFS][(ROFF) * 128] + dstB[1]);                                     \
} while (0)
#define READ_A(MQ, BUFC) do {                                                              \
    _Pragma("unroll") for (int i = 0; i < 4; ++i) {                                        \
        const char* _p = &ldsA[BUFC][(aRowBase + (MQ) * 64 + i * 16) * 128];               \
        aF[i][0] = *(const bf16x8_t*)(_p + kOff0);                                         \
        aF[i][1] = *(const bf16x8_t*)(_p + kOff1);                                         \
    }                                                                                      \
} while (0)
#define READ_B(NQ, BUFC) do {                                                              \
    _Pragma("unroll") for (int j = 0; j < 2; ++j) {                                        \
        const char* _p = &ldsB[BUFC][(bRowBase + ((NQ) * 2 + j) * 16) * 128];              \
        bF[(NQ) * 2 + j][0] = *(const bf16x8_t*)(_p + kOff0);                              \
        bF[(NQ) * 2 + j][1] = *(const bf16x8_t*)(_p + kOff1);                              \
    }                                                                                      \
} while (0)
#define MFMA_QUAD(MQ, NQ) do {                                                             \
    __builtin_amdgcn_s_setprio(1);                                                         \
    _Pragma("unroll") for (int i = 0; i < 4; ++i)                                          \
    _Pragma("unroll") for (int j = 0; j < 2; ++j)                                          \
    _Pragma("unroll") for (int kk = 0; kk < 2; ++kk)                                       \
        acc[(MQ) * 4 + i][(NQ) * 2 + j] = __builtin_amdgcn_mfma_f32_16x16x32_bf16(         \
            aF[i][kk], bF[(NQ) * 2 + j][kk], acc[(MQ) * 4 + i][(NQ) * 2 + j], 0, 0, 0);    \
    __builtin_amdgcn_s_setprio(0);                                                         \
} while (0)
#define BARRIER() asm volatile("s_barrier" ::: "memory")
#define VMCNT4()  asm volatile("s_waitcnt vmcnt(4)" ::: "memory")

#define KTILE(BUFC, KT, KTS) do {                                                          \
    /* ph0: quad (0,0) */                                                                  \
    READ_A(0, BUFC); READ_B(0, BUFC);                                                      \
    GL_A(KTS, (BUFC) ^ 1, 0);                                                              \
    VMCNT4(); BARRIER();                                                                   \
    MFMA_QUAD(0, 0);                                                                       \
    BARRIER();                                                                             \
    /* ph1: quad (0,1) */                                                                  \
    READ_B(1, BUFC);                                                                       \
    GL_B(KTS, (BUFC) ^ 1, 0);                                                              \
    VMCNT4(); BARRIER();                                                                   \
    MFMA_QUAD(0, 1);                                                                       \
    BARRIER();                                                                             \
    /* ph2: quad (1,1) */                                                                  \
    READ_A(1, BUFC);                                                                       \
    GL_B(KTS, (BUFC) ^ 1, 32);                                                             \
    BARRIER();                                                                             \
    MFMA_QUAD(1, 1);                                                                       \
    BARRIER();                                                                             \
    /* ph3: quad (1,0) — A(mq1), B(nq0) still in regs */                                   \
    GL_A(KTS, (BUFC) ^ 1, 64);                                                             \
    VMCNT4(); BARRIER();                                                                   \
    MFMA_QUAD(1, 0);                                                                       \
    BARRIER();                                                                             \
} while (0)

    // Prologue: stage tile 0 fully (order AQ0,BQ0,BQ1,AQ1), guarantee AQ0+BQ0.
    GL_A(0, 0, 0); GL_B(0, 0, 0); GL_B(0, 0, 32); GL_A(0, 0, 64);
    VMCNT4(); BARRIER();

#pragma unroll 1
    for (int kt = 0; kt < NTILES_K; kt += 2) {
        const int ks0 = kt + 1;                                   // < NTILES_K always
        const int ks1 = (kt + 2 < NTILES_K) ? kt + 2 : kt + 1;    // tail: restage (harmless)
        KTILE(0, kt, ks0);
        KTILE(1, kt + 1, ks1);
    }

    // Drain tail staging DMAs before the block can retire.
    asm volatile("s_waitcnt vmcnt(0)" ::: "memory");

    // Epilogue: C/D layout col=lane&15, row=(lane>>4)*4+reg.
#pragma unroll
    for (int m = 0; m < 8; ++m) {
        const size_t gr = (size_t)mt * 256 + wm * 128 + m * 16 + lq * 4;
#pragma unroll
        for (int n = 0; n < 4; ++n) {
            const size_t gc = (size_t)nt * 256 + wn * 64 + n * 16 + lr;
            float* cp = C + gr * N_DIM + gc;
#pragma unroll
            for (int rg = 0; rg < 4; ++rg)
                cp[(size_t)rg * N_DIM] = acc[m][n][rg];
        }
    }
}

// ---------------- fallback (ws too small / odd shape): fused fp32 ----------------
__global__ __launch_bounds__(256) void fallback_kernel(const float* __restrict__ x,
                                                       const int* __restrict__ qw,
                                                       const int* __restrict__ qz,
                                                       const float* __restrict__ sc,
                                                       float* __restrict__ out) {
    __shared__ float xrow[K_DIM];
    const int t = blockIdx.y;
    const int n = blockIdx.x * 256 + threadIdx.x;
    for (int i = threadIdx.x; i < K_DIM; i += 256)
        xrow[i] = x[(size_t)t * K_DIM + i];
    __syncthreads();
    if (n >= N_DIM) return;
    float acc = 0.f;
    for (int g = 0; g < K_DIM / GROUP_SZ; ++g) {
        float s = sc[(size_t)g * N_DIM + n];
        int z = (qz[(size_t)g * (N_DIM / 8) + (n >> 3)] >> ((n & 7) * 4)) & 15;
        float b = -(float)(z + 1) * s;
        for (int kp = g * 16; kp < g * 16 + 16; ++kp) {
            int q = qw[(size_t)kp * N_DIM + n];
#pragma unroll
            for (int j = 0; j < 8; ++j) {
                float w = (float)((q >> (4 * j)) & 15);
                acc = fmaf(xrow[kp * 8 + j], fmaf(w, s, b), acc);
            }
        }
    }
    out[(size_t)t * N_DIM + n] = acc;
}

extern "C" void kernel_launch(void* const* d_in, const int* in_sizes, int n_in,
                              void* d_out, int out_size, void* d_ws, size_t ws_size,
                              hipStream_t stream) {
    const float* x  = (const float*)d_in[0];
    const int*   qw = (const int*)d_in[1];
    const int*   qz = (const int*)d_in[2];
    const float* sc = (const float*)d_in[3];
    float* out = (float*)d_out;

    const long T = (long)in_sizes[0] / K_DIM;   // 8192
    const size_t xb_bytes = (size_t)T * K_DIM * sizeof(__bf16);
    const size_t wt_bytes = (size_t)N_DIM * K_DIM * sizeof(__bf16);

    if (ws_size >= xb_bytes + wt_bytes && (T % 256) == 0) {
        __bf16* xb = (__bf16*)d_ws;
        __bf16* Wt = (__bf16*)((char*)d_ws + xb_bytes);
        long total = T * K_DIM;
        long nthr = total / 8;
        convert_x_kernel<<<dim3((unsigned)((nthr + 255) / 256)), dim3(256), 0, stream>>>(x, xb, total);
        dequant_kernel<<<dim3(N_DIM / 128, K_DIM / GROUP_SZ), dim3(256), 0, stream>>>(qw, qz, sc, Wt);
        const int mtiles = (int)(T / 256);          // 32
        const int ntiles = N_DIM / 256;             // 43
        gemm256_kernel<<<dim3((unsigned)(mtiles * ntiles)), dim3(512), 0, stream>>>(xb, Wt, out, mtiles, ntiles);
    } else {
        fallback_kernel<<<dim3(N_DIM / 256 + 1, (unsigned)T), dim3(256), 0, stream>>>(x, qw, qz, sc, out);
    }
}

// Round 3
// 749.740 us; speedup vs baseline: 1.2952x; 1.0777x over previous
//
#include <hip/hip_runtime.h>
#include <hip/hip_bf16.h>
#include <cstdint>
#include <cstddef>

// GPTQ int4 linear: out[T,N] = x[T,K] @ dequant(qweight,qzeros,scales)
// T=8192, K=4096, N=11008, GROUP=128.
// Pipeline: x->bf16, dequant->W^T[N,K] bf16, then 256x256-tile 8-wave MFMA GEMM.
// R3: 1 barrier per phase (4/K-tile), counted vmcnt ledger, kk-outer MFMA order.

#define K_DIM 4096
#define N_DIM 11008
#define GROUP_SZ 128
#define KB (K_DIM * 2)        // bytes per row of a K-major bf16 panel
#define NTILES_K (K_DIM / 64) // 64 K-tiles of BK=64

typedef __bf16 bf16x8_t __attribute__((ext_vector_type(8)));
typedef float f32x4_t __attribute__((ext_vector_type(4)));

__device__ __forceinline__ void async_copy16(const void* g, void* l) {
    __builtin_amdgcn_global_load_lds((const __attribute__((address_space(1))) void*)g,
                                     (__attribute__((address_space(3))) void*)l,
                                     16, 0, 0);
}

// ---------------- x fp32 -> bf16 (vectorized) ----------------
__global__ __launch_bounds__(256) void convert_x_kernel(const float* __restrict__ x,
                                                        __bf16* __restrict__ xb,
                                                        long total) {
    long i = ((long)blockIdx.x * 256 + threadIdx.x) * 8;
    if (i >= total) return;
    const float4* p = (const float4*)(x + i);
    float4 u = p[0], v = p[1];
    bf16x8_t o;
    o[0] = (__bf16)u.x; o[1] = (__bf16)u.y; o[2] = (__bf16)u.z; o[3] = (__bf16)u.w;
    o[4] = (__bf16)v.x; o[5] = (__bf16)v.y; o[6] = (__bf16)v.z; o[7] = (__bf16)v.w;
    *(bf16x8_t*)(xb + i) = o;
}

// ---------------- GPTQ dequant -> W^T [N][K] bf16 ----------------
__global__ __launch_bounds__(256) void dequant_kernel(const int* __restrict__ qw,
                                                      const int* __restrict__ qz,
                                                      const float* __restrict__ sc,
                                                      __bf16* __restrict__ Wt) {
    __shared__ __align__(16) __bf16 dqT[128 * 136];  // [n][k] pad +8 bf16
    __shared__ float dqS[128];
    __shared__ float dqB[128];
    const int n0 = blockIdx.x * 128;
    const int g  = blockIdx.y;          // group index == k-tile (k0 = g*128)
    const int t  = threadIdx.x;

    if (t < 128) {
        int n = n0 + t;
        float s = sc[(size_t)g * N_DIM + n];
        int z = (qz[(size_t)g * (N_DIM / 8) + (n >> 3)] >> ((n & 7) * 4)) & 15;
        dqS[t] = s;
        dqB[t] = -(float)(z + 1) * s;     // GPTQ +1 zero offset
    }
    __syncthreads();

#pragma unroll
    for (int it = 0; it < 8; ++it) {
        int wi  = it * 256 + t;
        int row = wi >> 7;               // 0..15 (kp sub-row)
        int col = wi & 127;              // n sub-col
        int q = qw[(size_t)(g * 16 + row) * N_DIM + n0 + col];
        float s = dqS[col], b = dqB[col];
        bf16x8_t v;
#pragma unroll
        for (int j = 0; j < 8; ++j) {
            float w = (float)((q >> (4 * j)) & 15);
            v[j] = (__bf16)fmaf(w, s, b);
        }
        *(bf16x8_t*)(&dqT[col * 136 + row * 8]) = v;
    }
    __syncthreads();

    int n_loc = t & 127, half = t >> 7;
    const __bf16* src = &dqT[n_loc * 136 + half * 64];
    __bf16* dst = Wt + (size_t)(n0 + n_loc) * K_DIM + g * GROUP_SZ + half * 64;
#pragma unroll
    for (int i = 0; i < 8; ++i)
        *(bf16x8_t*)(dst + i * 8) = *(const bf16x8_t*)(src + i * 8);
}

// ---------------- 256x256 8-wave 4-phase MFMA GEMM ----------------
// C[T,N] = A[T,K] * Bt[N,K]^T.  8 waves as 2(M) x 4(N); wave tile 128x64.
// Per K-tile: 4 phases, ONE barrier each:
//   {ds_read subtile | stage 1 quadrant half-tile | counted vmcnt | barrier |
//    setprio + 16 MFMA}
// Ledger (2 loads/thread/GL): vmcnt(4)@ph0 guards BQ1(t) for ph1 reads;
// vmcnt(4)@ph1 guards AQ1(t) for ph2; none @ph2; vmcnt(4)@ph3 guards
// AQ0/BQ0(t+1) for next ph0. Never drains to 0 in the loop.
// Anti-hazard: a wave's ds_reads are lgkm-consumed before its MFMA, which
// precedes barrier_3, so all reads of buf complete chip-wide before ph0's
// global_load_lds overwrites it next tile.
__global__ __launch_bounds__(512, 2) void gemm256_kernel(const __bf16* __restrict__ A,
                                                         const __bf16* __restrict__ Bt,
                                                         float* __restrict__ C,
                                                         int mtiles, int ntiles) {
    __shared__ __align__(16) char ldsA[2][256 * 128];   // 64 KB
    __shared__ __align__(16) char ldsB[2][256 * 128];   // 64 KB
    const int tid = threadIdx.x;

    // T1: XCD chunking (bijective: grid % 8 == 0 here) + band supertiling for L3.
    const int nwg = gridDim.x;
    const int bid = blockIdx.x;
    int vid = (nwg & 7) ? bid : ((bid & 7) * (nwg >> 3) + (bid >> 3));
    int mt, nt;
    if ((mtiles & 15) == 0) {
        const int bandsz = 16 * ntiles;
        const int band = vid / bandsz, rem = vid % bandsz;
        nt = rem >> 4;
        mt = (band << 4) + (rem & 15);
    } else {
        mt = vid % mtiles;
        nt = vid / mtiles;
    }

    const char* aPanel = (const char*)A + (size_t)mt * 256 * KB;
    const char* bPanel = (const char*)Bt + (size_t)nt * 256 * KB;

    // Staging offsets. Quadrant row maps (preserve row&7 == r&7 so the XOR
    // swizzle mask matches the reader's (row&7)<<4):
    //   A-Q0: r + (r&64)   -> rows {0-63,128-191};  A-Q1 = +64
    //   B-Q0: r + (r&~31)  -> rows {0-31,64-95,128-159,192-223}; B-Q1 = +32
    // LDS dest is LINEAR in lane order (global_load_lds constraint); the
    // inverse XOR swizzle is applied to the GLOBAL source (both-sides rule).
    int srcA[2], srcB[2], dstA[2], dstB[2];
#pragma unroll
    for (int q = 0; q < 2; ++q) {
        const int f = q * 512 + tid;
        const int r = f >> 3, c = f & 7;
        const int swz = (c * 16) ^ ((r & 7) << 4);
        const int Ra = r + (r & 64);
        const int Rb = r + (r & ~31);
        srcA[q] = Ra * KB + swz;  dstA[q] = Ra * 128 + c * 16;
        srcB[q] = Rb * KB + swz;  dstB[q] = Rb * 128 + c * 16;
    }

    const int lane = tid & 63;
    const int wid = tid >> 6;
    const int wm = wid >> 2, wn = wid & 3;        // 2 x 4 waves
    const int lr = lane & 15, lq = lane >> 4;
    const int kOff0 = (lq * 16) ^ ((lr & 7) << 4);
    const int kOff1 = (64 + lq * 16) ^ ((lr & 7) << 4);
    const int aRowBase = wm * 128 + lr;           // + mq*64 + i*16
    const int bRowBase = wn * 64 + lr;            // + n*16

    bf16x8_t aF[4][2], bF[4][2];
    f32x4_t acc[8][4];
#pragma unroll
    for (int m = 0; m < 8; ++m)
#pragma unroll
        for (int n = 0; n < 4; ++n)
            acc[m][n] = (f32x4_t){0.f, 0.f, 0.f, 0.f};

#define GL_A(KT, BUFS, ROFF) do {                                                          \
    async_copy16(aPanel + (size_t)(KT) * 128 + (ROFF) * KB + srcA[0],                      \
                 &ldsA[BUFS][(ROFF) * 128] + dstA[0]);                                     \
    async_copy16(aPanel + (size_t)(KT) * 128 + (ROFF) * KB + srcA[1],                      \
                 &ldsA[BUFS][(ROFF) * 128] + dstA[1]);                                     \
} while (0)
#define GL_B(KT, BUFS, ROFF) do {                                                          \
    async_copy16(bPanel + (size_t)(KT) * 128 + (ROFF) * KB + srcB[0],                      \
                 &ldsB[BUFS][(ROFF) * 128] + dstB[0]);                                     \
    async_copy16(bPanel + (size_t)(KT) * 128 + (ROFF) * KB + srcB[1],                      \
                 &ldsB[BUFS][(ROFF) * 128] + dstB[1]);                                     \
} while (0)
#define READ_A(MQ, BUFC) do {                                                              \
    _Pragma("unroll") for (int i = 0; i < 4; ++i) {                                        \
        const char* _p = &ldsA[BUFC][(aRowBase + (MQ) * 64 + i * 16) * 128];               \
        aF[i][0] = *(const bf16x8_t*)(_p + kOff0);                                         \
        aF[i][1] = *(const bf16x8_t*)(_p + kOff1);                                         \
    }                                                                                      \
} while (0)
#define READ_B(NQ, BUFC) do {                                                              \
    _Pragma("unroll") for (int j = 0; j < 2; ++j) {                                        \
        const char* _p = &ldsB[BUFC][(bRowBase + ((NQ) * 2 + j) * 16) * 128];              \
        bF[(NQ) * 2 + j][0] = *(const bf16x8_t*)(_p + kOff0);                              \
        bF[(NQ) * 2 + j][1] = *(const bf16x8_t*)(_p + kOff1);                              \
    }                                                                                      \
} while (0)
// kk OUTER: same-accumulator MFMAs are 8 apart (no back-to-back acc dependency)
#define MFMA_QUAD(MQ, NQ) do {                                                             \
    __builtin_amdgcn_s_setprio(1);                                                         \
    _Pragma("unroll") for (int kk = 0; kk < 2; ++kk)                                       \
    _Pragma("unroll") for (int i = 0; i < 4; ++i)                                          \
    _Pragma("unroll") for (int j = 0; j < 2; ++j)                                          \
        acc[(MQ) * 4 + i][(NQ) * 2 + j] = __builtin_amdgcn_mfma_f32_16x16x32_bf16(         \
            aF[i][kk], bF[(NQ) * 2 + j][kk], acc[(MQ) * 4 + i][(NQ) * 2 + j], 0, 0, 0);    \
    __builtin_amdgcn_s_setprio(0);                                                         \
} while (0)
#define BARRIER() asm volatile("s_barrier" ::: "memory")
#define VMCNT4()  asm volatile("s_waitcnt vmcnt(4)" ::: "memory")

#define KTILE(BUFC, KTS) do {                                                              \
    /* ph0: quad (0,0) */                                                                  \
    READ_A(0, BUFC); READ_B(0, BUFC);                                                      \
    GL_A(KTS, (BUFC) ^ 1, 0);                                                              \
    VMCNT4(); BARRIER();                                                                   \
    MFMA_QUAD(0, 0);                                                                       \
    /* ph1: quad (0,1) */                                                                  \
    READ_B(1, BUFC);                                                                       \
    GL_B(KTS, (BUFC) ^ 1, 0);                                                              \
    VMCNT4(); BARRIER();                                                                   \
    MFMA_QUAD(0, 1);                                                                       \
    /* ph2: quad (1,1) */                                                                  \
    READ_A(1, BUFC);                                                                       \
    GL_B(KTS, (BUFC) ^ 1, 32);                                                             \
    BARRIER();                                                                             \
    MFMA_QUAD(1, 1);                                                                       \
    /* ph3: quad (1,0) — A(mq1), B(nq0) still in regs */                                   \
    GL_A(KTS, (BUFC) ^ 1, 64);                                                             \
    VMCNT4(); BARRIER();                                                                   \
    MFMA_QUAD(1, 0);                                                                       \
} while (0)

    // Prologue: stage tile 0 fully (order AQ0,BQ0,BQ1,AQ1), guarantee AQ0+BQ0.
    GL_A(0, 0, 0); GL_B(0, 0, 0); GL_B(0, 0, 32); GL_A(0, 0, 64);
    VMCNT4(); BARRIER();

#pragma unroll 1
    for (int kt = 0; kt < NTILES_K; kt += 2) {
        const int ks0 = kt + 1;                                   // < NTILES_K always
        const int ks1 = (kt + 2 < NTILES_K) ? kt + 2 : kt + 1;    // tail: restage (harmless)
        KTILE(0, ks0);
        KTILE(1, ks1);
    }

    // Drain tail staging DMAs before the block can retire.
    asm volatile("s_waitcnt vmcnt(0)" ::: "memory");

    // Epilogue: C/D layout col=lane&15, row=(lane>>4)*4+reg.
#pragma unroll
    for (int m = 0; m < 8; ++m) {
        const size_t gr = (size_t)mt * 256 + wm * 128 + m * 16 + lq * 4;
#pragma unroll
        for (int n = 0; n < 4; ++n) {
            const size_t gc = (size_t)nt * 256 + wn * 64 + n * 16 + lr;
            float* cp = C + gr * N_DIM + gc;
#pragma unroll
            for (int rg = 0; rg < 4; ++rg)
                cp[(size_t)rg * N_DIM] = acc[m][n][rg];
        }
    }
}

// ---------------- fallback (ws too small / odd shape): fused fp32 ----------------
__global__ __launch_bounds__(256) void fallback_kernel(const float* __restrict__ x,
                                                       const int* __restrict__ qw,
                                                       const int* __restrict__ qz,
                                                       const float* __restrict__ sc,
                                                       float* __restrict__ out) {
    __shared__ float xrow[K_DIM];
    const int t = blockIdx.y;
    const int n = blockIdx.x * 256 + threadIdx.x;
    for (int i = threadIdx.x; i < K_DIM; i += 256)
        xrow[i] = x[(size_t)t * K_DIM + i];
    __syncthreads();
    if (n >= N_DIM) return;
    float acc = 0.f;
    for (int g = 0; g < K_DIM / GROUP_SZ; ++g) {
        float s = sc[(size_t)g * N_DIM + n];
        int z = (qz[(size_t)g * (N_DIM / 8) + (n >> 3)] >> ((n & 7) * 4)) & 15;
        float b = -(float)(z + 1) * s;
        for (int kp = g * 16; kp < g * 16 + 16; ++kp) {
            int q = qw[(size_t)kp * N_DIM + n];
#pragma unroll
            for (int j = 0; j < 8; ++j) {
                float w = (float)((q >> (4 * j)) & 15);
                acc = fmaf(xrow[kp * 8 + j], fmaf(w, s, b), acc);
            }
        }
    }
    out[(size_t)t * N_DIM + n] = acc;
}

extern "C" void kernel_launch(void* const* d_in, const int* in_sizes, int n_in,
                              void* d_out, int out_size, void* d_ws, size_t ws_size,
                              hipStream_t stream) {
    const float* x  = (const float*)d_in[0];
    const int*   qw = (const int*)d_in[1];
    const int*   qz = (const int*)d_in[2];
    const float* sc = (const float*)d_in[3];
    float* out = (float*)d_out;

    const long T = (long)in_sizes[0] / K_DIM;   // 8192
    const size_t xb_bytes = (size_t)T * K_DIM * sizeof(__bf16);
    const size_t wt_bytes = (size_t)N_DIM * K_DIM * sizeof(__bf16);

    if (ws_size >= xb_bytes + wt_bytes && (T % 256) == 0) {
        __bf16* xb = (__bf16*)d_ws;
        __bf16* Wt = (__bf16*)((char*)d_ws + xb_bytes);
        long total = T * K_DIM;
        long nthr = total / 8;
        convert_x_kernel<<<dim3((unsigned)((nthr + 255) / 256)), dim3(256), 0, stream>>>(x, xb, total);
        dequant_kernel<<<dim3(N_DIM / 128, K_DIM / GROUP_SZ), dim3(256), 0, stream>>>(qw, qz, sc, Wt);
        const int mtiles = (int)(T / 256);          // 32
        const int ntiles = N_DIM / 256;             // 43
        gemm256_kernel<<<dim3((unsigned)(mtiles * ntiles)), dim3(512), 0, stream>>>(xb, Wt, out, mtiles, ntiles);
    } else {
        fallback_kernel<<<dim3(N_DIM / 256 + 1, (unsigned)T), dim3(256), 0, stream>>>(x, qw, qz, sc, out);
    }
}